// Round 15
// baseline (410.144 us; speedup 1.0000x reference)
//
#include <hip/hip_runtime.h>
#include <hip/hip_bf16.h>
#include <math.h>

// Problem constants (match reference setup_inputs()).
#define N_NODES 20000
#define N_EDGES 320000
#define N_GRAPHS 64
#define SEQ 20
#define SCALAR 16
#define EMB 32
#define HID 128
#define IN_DIM 176         // SCALAR + 5*EMB
#define TOT_EDGES (N_EDGES + N_NODES)  // with self loops
#define CHUNK_SMALL 10000  // fallback node chunk when workspace is tight

// f16 MFMA types
typedef _Float16 half8v __attribute__((ext_vector_type(8)));
typedef float f32x4 __attribute__((ext_vector_type(4)));
#define LO_SCALE 2048.0f
#define LO_INV (1.0f / 2048.0f)

// Pack-buffer element counts (f16 elems each, hi and lo separately)
#define PB2_ELEMS (16 * 8 * 64 * 8)      // [ks16][ntile8][lane64][j8] = 65536
#define PB1_ELEMS (4 * 6 * 8 * 64 * 8)   // [head4][ks6][ntile8][lane64][j8] = 98304

// Grid split constants.
#define COUNT_BLOCKS ((TOT_EDGES + 255) / 256)  // 1329
#define NB4 ((N_NODES + 3) / 4)               // 5000 feats blocks
// L1 layout: [0,NB4) feats; [NB4,NB4+48) pack_w1; [+32) pack_w2;
//            [+COUNT_BLOCKS) count.
#define L1_PACK1 NB4
#define L1_PACK2 (NB4 + 48)
#define L1_COUNT (NB4 + 80)
#define L1_TOTAL (NB4 + 80 + COUNT_BLOCKS)

__device__ inline float readlane_f(float v, int l) {
  return __uint_as_float(__builtin_amdgcn_readlane(__float_as_uint(v), l));
}
__device__ inline int readlane_i(int v, int l) {
  return __builtin_amdgcn_readlane(v, l);
}
__device__ inline float leaky(float e) { return e >= 0.f ? e : 0.2f * e; }
__device__ inline float elu(float v) { return v > 0.f ? v : expf(v) - 1.f; }

// Order-preserving float<->uint bijection (for atomicMax pooling; EXACT).
__device__ inline unsigned encf(float x) {
  unsigned b = __float_as_uint(x);
  return (b & 0x80000000u) ? ~b : (b | 0x80000000u);
}
__device__ inline float decf(unsigned e) {
  return __uint_as_float((e & 0x80000000u) ? (e & 0x7FFFFFFFu) : ~e);
}

// ---------------------------------------------------------------------------
// L0: wasd precompute alone (feats' only dependency). 44 blocks.
// ---------------------------------------------------------------------------
__global__ __launch_bounds__(256) void wasd_kernel(
    const float* __restrict__ W1, const float* __restrict__ att_s1,
    const float* __restrict__ att_d1, float* __restrict__ was4,
    float* __restrict__ wad4) {
  int lane = threadIdx.x & 63;
  int k = blockIdx.x * 4 + (threadIdx.x >> 6);
  if (k >= IN_DIM) return;
  const float* wrow = W1 + (size_t)k * 512;
  float s[4], d[4];
#pragma unroll
  for (int hh = 0; hh < 4; ++hh) {
    float w0 = wrow[hh * 128 + lane], w1 = wrow[hh * 128 + 64 + lane];
    float a0 = att_s1[hh * 128 + lane], a1 = att_s1[hh * 128 + 64 + lane];
    float c0 = att_d1[hh * 128 + lane], c1 = att_d1[hh * 128 + 64 + lane];
    s[hh] = w0 * a0 + w1 * a1;
    d[hh] = w0 * c0 + w1 * c1;
  }
  for (int off = 1; off < 64; off <<= 1) {
#pragma unroll
    for (int hh = 0; hh < 4; ++hh) {
      s[hh] += __shfl_xor(s[hh], off);
      d[hh] += __shfl_xor(d[hh], off);
    }
  }
  if (lane == 0) {
    *(float4*)&was4[k * 4] = make_float4(s[0], s[1], s[2], s[3]);
    *(float4*)&wad4[k * 4] = make_float4(d[0], d[1], d[2], d[3]);
  }
}

// ---------------------------------------------------------------------------
// L1 (fused): feats+LN+att1 FIRST (5000 long blocks), then pack_w1/pack_w2,
// CSR degree count. All parts' inputs ready (wasd in L0; cnt pre-zeroed).
// ---------------------------------------------------------------------------
__global__ __launch_bounds__(256) void feats_setup_kernel(
    const float* __restrict__ xs,
    const int* __restrict__ i0, const int* __restrict__ i1,
    const int* __restrict__ i2, const int* __restrict__ i3,
    const int* __restrict__ i4,
    const float* __restrict__ t0, const float* __restrict__ t1,
    const float* __restrict__ t2, const float* __restrict__ t3,
    const float* __restrict__ t4,
    const float* __restrict__ gamma, const float* __restrict__ beta,
    const float* __restrict__ was4, const float* __restrict__ wad4,
    const float* __restrict__ W1, const float* __restrict__ W2,
    const int* __restrict__ edge_index,
    float* __restrict__ hout, float* __restrict__ a_s,
    float* __restrict__ a_d,
    _Float16* __restrict__ PB1h, _Float16* __restrict__ PB1l,
    _Float16* __restrict__ PB2h, _Float16* __restrict__ PB2l,
    int* __restrict__ cnt) {
  int b = blockIdx.x;
  if (b >= NB4) {
    if (b < L1_PACK2) {
      // pack_w1: [hh4][ks6][ntile8][lane64][j8], K zero-padded to 192.
      int t = (b - L1_PACK1) * 256 + threadIdx.x;  // 12288 threads exactly
      int lane = t & 63, wi = t >> 6;
      int r = lane & 15, g = lane >> 4;
      int ntile = wi & 7, rem = wi >> 3;
      int ks = rem % 6, hh = rem / 6;
      int col = hh * 128 + ntile * 16 + r;
      size_t o = ((size_t)wi * 64 + lane) * 8;
#pragma unroll
      for (int j = 0; j < 8; ++j) {
        int k = ks * 32 + g * 8 + j;
        float v = (k < IN_DIM) ? W1[(size_t)k * 512 + col] : 0.f;
        _Float16 h = (_Float16)v;
        PB1h[o + j] = h;
        PB1l[o + j] = (_Float16)((v - (float)h) * LO_SCALE);
      }
    } else if (b < L1_COUNT) {
      // pack_w2: [ks16][ntile8][lane64][j8]
      int t = (b - L1_PACK2) * 256 + threadIdx.x;  // 8192 threads exactly
      int lane = t & 63, wi = t >> 6;
      int r = lane & 15, g = lane >> 4;
      int ks = wi >> 3, ntile = wi & 7;
      int col = ntile * 16 + r;
      size_t o = ((size_t)wi * 64 + lane) * 8;
#pragma unroll
      for (int j = 0; j < 8; ++j) {
        int k = ks * 32 + g * 8 + j;
        float v = W2[(size_t)k * 128 + col];
        _Float16 h = (_Float16)v;
        PB2h[o + j] = h;
        PB2l[o + j] = (_Float16)((v - (float)h) * LO_SCALE);
      }
    } else {
      // CSR degree count (cnt pre-zeroed by memset).
      int i = (b - L1_COUNT) * 256 + threadIdx.x;
      if (i < N_EDGES) {
        atomicAdd(&cnt[edge_index[N_EDGES + i]], 1);
      } else if (i < TOT_EDGES) {
        atomicAdd(&cnt[i - N_EDGES], 1);  // self loop dst = node
      }
    }
    return;
  }
  // feats+LN+att1, wave-per-node (4 nodes / block, zero barriers).
  int lane = threadIdx.x & 63;
  int w = threadIdx.x >> 6;
  int n = b * 4 + w;
  if (n >= N_NODES) return;
  __shared__ int sidx[4][100];
  {
    int j = lane;                       // 0..63 -> tabs 0..3
    int tab = j / 20, l = j - tab * 20;
    const int* ip = tab == 0 ? i0 : tab == 1 ? i1 : tab == 2 ? i2 : i3;
    sidx[w][j] = ip[n * SEQ + l];
    if (lane < 36) {
      int j2 = 64 + lane;               // 64..99 -> tabs 3,4
      int tab2 = j2 / 20, l2 = j2 - tab2 * 20;
      const int* ip2 = tab2 == 3 ? i3 : i4;
      sidx[w][j2] = ip2[n * SEQ + l2];
    }
  }
  bool l48 = lane < 48;
  float f0, f1, f2 = 0.f;
  if (lane < SCALAR) {
    f0 = xs[n * SCALAR + lane];
  } else {
    int tt = lane - SCALAR, tab = tt >> 5, d = tt & 31;  // tab 0 or 1
    const float* tp = tab == 0 ? t0 : t1;
    float sum = 0.f, cnt2 = 0.f;
#pragma unroll
    for (int l = 0; l < SEQ; ++l) {
      int id = sidx[w][tab * 20 + l];
      if (id != 0) { sum += tp[id * EMB + d]; cnt2 += 1.f; }
    }
    f0 = sum / (cnt2 + 1e-9f);
  }
  {
    int tt = 48 + lane, tab = tt >> 5, d = tt & 31;      // tab 1,2,3
    const float* tp = tab == 1 ? t1 : tab == 2 ? t2 : t3;
    float sum = 0.f, cnt2 = 0.f;
#pragma unroll
    for (int l = 0; l < SEQ; ++l) {
      int id = sidx[w][tab * 20 + l];
      if (id != 0) { sum += tp[id * EMB + d]; cnt2 += 1.f; }
    }
    f1 = sum / (cnt2 + 1e-9f);
  }
  if (l48) {
    int tt = 112 + lane, tab = tt >> 5, d = tt & 31;     // tab 3 or 4
    const float* tp = tab == 3 ? t3 : t4;
    float sum = 0.f, cnt2 = 0.f;
#pragma unroll
    for (int l = 0; l < SEQ; ++l) {
      int id = sidx[w][tab * 20 + l];
      if (id != 0) { sum += tp[id * EMB + d]; cnt2 += 1.f; }
    }
    f2 = sum / (cnt2 + 1e-9f);
  }
  float s = f0 + f1 + f2;  // f2==0 for lane>=48
  for (int off = 1; off < 64; off <<= 1) s += __shfl_xor(s, off);
  float mu = s / (float)IN_DIM;
  float v = (f0 - mu) * (f0 - mu) + (f1 - mu) * (f1 - mu) +
            (l48 ? (f2 - mu) * (f2 - mu) : 0.f);
  for (int off = 1; off < 64; off <<= 1) v += __shfl_xor(v, off);
  float rstd = 1.0f / sqrtf(v / (float)IN_DIM + 1e-5f);
  float hv0 = (f0 - mu) * rstd * gamma[lane] + beta[lane];
  float hv1 = (f1 - mu) * rstd * gamma[64 + lane] + beta[64 + lane];
  float hv2 = l48 ? (f2 - mu) * rstd * gamma[128 + lane] + beta[128 + lane] : 0.f;
  float* hr = hout + (size_t)n * IN_DIM;
  hr[lane] = hv0;
  hr[64 + lane] = hv1;
  if (l48) hr[128 + lane] = hv2;

  // Fused layer-1 attention logits: ps/pd[h] = h_row . was/wad[:,h]
  const float4* wsv = (const float4*)was4;
  const float4* wdv = (const float4*)wad4;
  float4 wsa = wsv[lane], wsb = wsv[64 + lane];
  float4 wsc = l48 ? wsv[128 + lane] : make_float4(0.f, 0.f, 0.f, 0.f);
  float4 wda = wdv[lane], wdb = wdv[64 + lane];
  float4 wdc = l48 ? wdv[128 + lane] : make_float4(0.f, 0.f, 0.f, 0.f);
  float ps0 = hv0 * wsa.x + hv1 * wsb.x + hv2 * wsc.x;
  float ps1 = hv0 * wsa.y + hv1 * wsb.y + hv2 * wsc.y;
  float ps2 = hv0 * wsa.z + hv1 * wsb.z + hv2 * wsc.z;
  float ps3 = hv0 * wsa.w + hv1 * wsb.w + hv2 * wsc.w;
  float pd0 = hv0 * wda.x + hv1 * wdb.x + hv2 * wdc.x;
  float pd1 = hv0 * wda.y + hv1 * wdb.y + hv2 * wdc.y;
  float pd2 = hv0 * wda.z + hv1 * wdb.z + hv2 * wdc.z;
  float pd3 = hv0 * wda.w + hv1 * wdb.w + hv2 * wdc.w;
  for (int off = 1; off < 64; off <<= 1) {
    ps0 += __shfl_xor(ps0, off); ps1 += __shfl_xor(ps1, off);
    ps2 += __shfl_xor(ps2, off); ps3 += __shfl_xor(ps3, off);
    pd0 += __shfl_xor(pd0, off); pd1 += __shfl_xor(pd1, off);
    pd2 += __shfl_xor(pd2, off); pd3 += __shfl_xor(pd3, off);
  }
  if (lane == 0) {
    *(float4*)&a_s[n * 4] = make_float4(ps0, ps1, ps2, ps3);
    *(float4*)&a_d[n * 4] = make_float4(pd0, pd1, pd2, pd3);
  }
}

// ---------------------------------------------------------------------------
// 1024-thread single block: per-thread partial sums + Hillis-Steele scan.
// ---------------------------------------------------------------------------
__global__ __launch_bounds__(1024) void prefix_kernel(const int* __restrict__ cnt,
                                                      int* __restrict__ indptr,
                                                      int n, int total) {
  __shared__ int ss[1024];
  int t = threadIdx.x;
  int per = (n + 1023) / 1024;
  int beg = t * per, end = min(beg + per, n);
  int s = 0;
  for (int i = beg; i < end; ++i) s += cnt[i];
  ss[t] = s;
  __syncthreads();
  for (int off = 1; off < 1024; off <<= 1) {
    int v = (t >= off) ? ss[t - off] : 0;
    __syncthreads();
    ss[t] += v;
    __syncthreads();
  }
  int run = ss[t] - s;  // exclusive prefix of this thread's range
  for (int i = beg; i < end; ++i) { indptr[i] = run; run += cnt[i]; }
  if (t == 0) indptr[n] = total;
}

// ---------------------------------------------------------------------------
// L3: CSR scatter alone (needs prefix). 1329 blocks, full machine.
// ---------------------------------------------------------------------------
__global__ void scatter_kernel(const int* __restrict__ edge_index,
                               const int* __restrict__ indptr,
                               int* __restrict__ cursor,
                               int* __restrict__ srcs) {
  int i = blockIdx.x * 256 + threadIdx.x;
  int s, d;
  if (i < N_EDGES) { s = edge_index[i]; d = edge_index[N_EDGES + i]; }
  else if (i < TOT_EDGES) { s = i - N_EDGES; d = s; }
  else return;
  int pos = indptr[d] + atomicAdd(&cursor[d], 1);
  srcs[pos] = s;
}

// ---------------------------------------------------------------------------
// Layer-1 softmax + aggregate h (176-dim) per head.
// Output PRE-SPLIT as f16 hi/lo planes (agghh/agghl, lo scaled x2048).
// ---------------------------------------------------------------------------
__global__ __launch_bounds__(256) void agg1h_kernel(
    const float* __restrict__ h, const float* __restrict__ a_src,
    const float* __restrict__ a_dst, const int* __restrict__ indptr,
    const int* __restrict__ srcs, _Float16* __restrict__ agghh,
    _Float16* __restrict__ agghl, int n0, int nM) {
  int lane = threadIdx.x & 63;
  int ln = blockIdx.x * 4 + (threadIdx.x >> 6);
  if (ln >= nM) return;
  int n = n0 + ln;
  int beg = indptr[n], end = indptr[n + 1];
  int deg = end - beg;
  float4 ad = *(const float4*)&a_dst[n * 4];
  bool l48 = lane < 48;
  float acc[4][3] = {};

  auto body = [&](int s, float al0, float al1, float al2, float al3) {
    const float* r = h + (size_t)s * IN_DIM;
    float v0 = r[lane];
    float v1 = r[64 + lane];
    float v2 = l48 ? r[128 + lane] : 0.f;
    acc[0][0] += al0 * v0; acc[0][1] += al0 * v1; acc[0][2] += al0 * v2;
    acc[1][0] += al1 * v0; acc[1][1] += al1 * v1; acc[1][2] += al1 * v2;
    acc[2][0] += al2 * v0; acc[2][1] += al2 * v1; acc[2][2] += al2 * v2;
    acc[3][0] += al3 * v0; acc[3][1] += al3 * v1; acc[3][2] += al3 * v2;
  };
  auto walk4 = [&](int s, float al0, float al1, float al2, float al3, int jn) {
    int jj = 0;
    for (; jj + 4 <= jn; jj += 4) {
      int sa = readlane_i(s, jj), sb = readlane_i(s, jj + 1);
      int sc = readlane_i(s, jj + 2), sd = readlane_i(s, jj + 3);
      float a0 = readlane_f(al0, jj), a1 = readlane_f(al1, jj);
      float a2 = readlane_f(al2, jj), a3 = readlane_f(al3, jj);
      float b0 = readlane_f(al0, jj + 1), b1 = readlane_f(al1, jj + 1);
      float b2 = readlane_f(al2, jj + 1), b3 = readlane_f(al3, jj + 1);
      float c0 = readlane_f(al0, jj + 2), c1 = readlane_f(al1, jj + 2);
      float c2 = readlane_f(al2, jj + 2), c3 = readlane_f(al3, jj + 2);
      float d0 = readlane_f(al0, jj + 3), d1 = readlane_f(al1, jj + 3);
      float d2 = readlane_f(al2, jj + 3), d3 = readlane_f(al3, jj + 3);
      body(sa, a0, a1, a2, a3);
      body(sb, b0, b1, b2, b3);
      body(sc, c0, c1, c2, c3);
      body(sd, d0, d1, d2, d3);
    }
    for (; jj < jn; ++jj) {
      int sa = readlane_i(s, jj);
      body(sa, readlane_f(al0, jj), readlane_f(al1, jj),
           readlane_f(al2, jj), readlane_f(al3, jj));
    }
  };

  if (deg <= 64) {
    int j = beg + lane;
    int s = 0;
    float e0 = -INFINITY, e1 = -INFINITY, e2 = -INFINITY, e3 = -INFINITY;
    if (j < end) {
      s = srcs[j];
      float4 as = *(const float4*)&a_src[s * 4];
      e0 = leaky(as.x + ad.x); e1 = leaky(as.y + ad.y);
      e2 = leaky(as.z + ad.z); e3 = leaky(as.w + ad.w);
    }
    float m0 = e0, m1 = e1, m2 = e2, m3 = e3;
    for (int off = 1; off < 64; off <<= 1) {
      m0 = fmaxf(m0, __shfl_xor(m0, off)); m1 = fmaxf(m1, __shfl_xor(m1, off));
      m2 = fmaxf(m2, __shfl_xor(m2, off)); m3 = fmaxf(m3, __shfl_xor(m3, off));
    }
    float x0 = (j < end) ? expf(e0 - m0) : 0.f;
    float x1 = (j < end) ? expf(e1 - m1) : 0.f;
    float x2 = (j < end) ? expf(e2 - m2) : 0.f;
    float x3 = (j < end) ? expf(e3 - m3) : 0.f;
    float d0 = x0, d1 = x1, d2 = x2, d3 = x3;
    for (int off = 1; off < 64; off <<= 1) {
      d0 += __shfl_xor(d0, off); d1 += __shfl_xor(d1, off);
      d2 += __shfl_xor(d2, off); d3 += __shfl_xor(d3, off);
    }
    float al0 = x0 / (d0 + 1e-16f), al1 = x1 / (d1 + 1e-16f);
    float al2 = x2 / (d2 + 1e-16f), al3 = x3 / (d3 + 1e-16f);
    walk4(s, al0, al1, al2, al3, deg);
  } else {
    float m0 = -INFINITY, m1 = -INFINITY, m2 = -INFINITY, m3 = -INFINITY;
    for (int j0 = beg; j0 < end; j0 += 64) {
      int j = j0 + lane;
      if (j < end) {
        int s = srcs[j];
        float4 as = *(const float4*)&a_src[s * 4];
        m0 = fmaxf(m0, leaky(as.x + ad.x)); m1 = fmaxf(m1, leaky(as.y + ad.y));
        m2 = fmaxf(m2, leaky(as.z + ad.z)); m3 = fmaxf(m3, leaky(as.w + ad.w));
      }
    }
    for (int off = 1; off < 64; off <<= 1) {
      m0 = fmaxf(m0, __shfl_xor(m0, off)); m1 = fmaxf(m1, __shfl_xor(m1, off));
      m2 = fmaxf(m2, __shfl_xor(m2, off)); m3 = fmaxf(m3, __shfl_xor(m3, off));
    }
    float d0 = 0.f, d1 = 0.f, d2 = 0.f, d3 = 0.f;
    for (int j0 = beg; j0 < end; j0 += 64) {
      int j = j0 + lane;
      if (j < end) {
        int s = srcs[j];
        float4 as = *(const float4*)&a_src[s * 4];
        d0 += expf(leaky(as.x + ad.x) - m0); d1 += expf(leaky(as.y + ad.y) - m1);
        d2 += expf(leaky(as.z + ad.z) - m2); d3 += expf(leaky(as.w + ad.w) - m3);
      }
    }
    for (int off = 1; off < 64; off <<= 1) {
      d0 += __shfl_xor(d0, off); d1 += __shfl_xor(d1, off);
      d2 += __shfl_xor(d2, off); d3 += __shfl_xor(d3, off);
    }
    float r0 = 1.f / (d0 + 1e-16f), r1 = 1.f / (d1 + 1e-16f);
    float r2 = 1.f / (d2 + 1e-16f), r3 = 1.f / (d3 + 1e-16f);
    for (int j0 = beg; j0 < end; j0 += 64) {
      int jn = min(64, end - j0);
      int j = j0 + lane;
      int s = 0;
      float al0 = 0.f, al1 = 0.f, al2 = 0.f, al3 = 0.f;
      if (j < end) {
        s = srcs[j];
        float4 as = *(const float4*)&a_src[s * 4];
        al0 = expf(leaky(as.x + ad.x) - m0) * r0;
        al1 = expf(leaky(as.y + ad.y) - m1) * r1;
        al2 = expf(leaky(as.z + ad.z) - m2) * r2;
        al3 = expf(leaky(as.w + ad.w) - m3) * r3;
      }
      walk4(s, al0, al1, al2, al3, jn);
    }
  }

  size_t base = (size_t)ln * (4 * IN_DIM);
#pragma unroll
  for (int hh = 0; hh < 4; ++hh) {
    size_t o0 = base + hh * IN_DIM + lane;
    float v0 = acc[hh][0], v1 = acc[hh][1];
    _Float16 h0 = (_Float16)v0, h1 = (_Float16)v1;
    agghh[o0] = h0;      agghl[o0] = (_Float16)((v0 - (float)h0) * LO_SCALE);
    agghh[o0 + 64] = h1; agghl[o0 + 64] = (_Float16)((v1 - (float)h1) * LO_SCALE);
    if (l48) {
      float v2 = acc[hh][2];
      _Float16 h2 = (_Float16)v2;
      agghh[o0 + 128] = h2;
      agghl[o0 + 128] = (_Float16)((v2 - (float)h2) * LO_SCALE);
    }
  }
}

// ---------------------------------------------------------------------------
// FUSED GEMM1+GEMM2, 32 ROWS/BLOCK. 512 threads = 8 waves; stage 1 wave
// w=(hh,colhalf) computes TWO 16-row groups; stage 2 wave w computes cols
// [w*16,+16) for 32 rows from LDS. Conversion-free both stages; out1 never
// touches HBM. Tail guard: rows >= nM never written.
// ---------------------------------------------------------------------------
__global__ __launch_bounds__(512) void gemm_fused_kernel(
    const _Float16* __restrict__ Ah, const _Float16* __restrict__ Al,
    const half8v* __restrict__ PB1h, const half8v* __restrict__ PB1l,
    const float* __restrict__ b1,
    const half8v* __restrict__ PB2h, const half8v* __restrict__ PB2l,
    const float* __restrict__ att_s, const float* __restrict__ att_d,
    float* __restrict__ xw2, float* __restrict__ a_s, float* __restrict__ a_d,
    int n0, int nM) {
  __shared__ _Float16 s1h[32][520];   // stride 520: 16B-aligned rows
  __shared__ _Float16 s1l[32][520];
  int lane = threadIdx.x & 63;
  int w = threadIdx.x >> 6;          // wave 0..7
  int rows0 = blockIdx.x * 32;
  if (rows0 >= nM) return;           // uniform per block
  int r = lane & 15, g = lane >> 4;
  // Clamp row-group-1 A pointers on the CHUNK_SMALL tail (discarded rows).
  int r1 = (rows0 + 16 + r < nM) ? (rows0 + 16 + r) : (rows0 + r);

  // ---- stage 1: out1[rows0..rows0+32) x (head hh, colhalf) ----
  {
    int hh = w >> 1, colhalf = w & 1;
    f32x4 acc[2][4] = {};
    f32x4 accm[2][4] = {};
    const _Float16* a0h = Ah + ((size_t)(rows0 + r) * 4 + hh) * IN_DIM;
    const _Float16* a0l = Al + ((size_t)(rows0 + r) * 4 + hh) * IN_DIM;
    const _Float16* a1h = Ah + ((size_t)r1 * 4 + hh) * IN_DIM;
    const _Float16* a1l = Al + ((size_t)r1 * 4 + hh) * IN_DIM;
#pragma unroll 2
    for (int ks = 0; ks < 6; ++ks) {
      int kg = ks * 32 + g * 8;
      int koff = (kg + 8 <= IN_DIM) ? kg : 0;  // clamp tail (B zeros kill it)
      half8v ah0 = *(const half8v*)(a0h + koff);
      half8v al0 = *(const half8v*)(a0l + koff);
      half8v ah1 = *(const half8v*)(a1h + koff);
      half8v al1 = *(const half8v*)(a1l + koff);
      const half8v* bh = PB1h + (size_t)(((hh * 6 + ks) * 8 + colhalf * 4) * 64) + lane;
      const half8v* bl = PB1l + (size_t)(((hh * 6 + ks) * 8 + colhalf * 4) * 64) + lane;
#pragma unroll
      for (int nt = 0; nt < 4; ++nt) {
        half8v bhv = bh[nt * 64], blv = bl[nt * 64];
        accm[0][nt] = __builtin_amdgcn_mfma_f32_16x16x32_f16(al0, bhv, accm[0][nt], 0, 0, 0);
        accm[0][nt] = __builtin_amdgcn_mfma_f32_16x16x32_f16(ah0, blv, accm[0][nt], 0, 0, 0);
        acc[0][nt]  = __builtin_amdgcn_mfma_f32_16x16x32_f16(ah0, bhv, acc[0][nt], 0, 0, 0);
        accm[1][nt] = __builtin_amdgcn_mfma_f32_16x16x32_f16(al1, bhv, accm[1][nt], 0, 0, 0);
        accm[1][nt] = __builtin_amdgcn_mfma_f32_16x16x32_f16(ah1, blv, accm[1][nt], 0, 0, 0);
        acc[1][nt]  = __builtin_amdgcn_mfma_f32_16x16x32_f16(ah1, bhv, acc[1][nt], 0, 0, 0);
      }
    }
#pragma unroll
    for (int nt = 0; nt < 4; ++nt) {
      int col = hh * 128 + colhalf * 64 + nt * 16 + r;
      float bb = b1[col];
#pragma unroll
      for (int mt = 0; mt < 2; ++mt) {
#pragma unroll
        for (int i = 0; i < 4; ++i) {
          int row = mt * 16 + g * 4 + i;  // 0..31 block-local
          if (rows0 + row < nM) {
            float o = elu(acc[mt][nt][i] + accm[mt][nt][i] * LO_INV + bb);
            _Float16 oh = (_Float16)o;
            s1h[row][col] = oh;
            s1l[row][col] = (_Float16)((o - (float)oh) * LO_SCALE);
          }
        }
      }
    }
  }
  __syncthreads();

  // ---- stage 2: xw2 cols [w*16, w*16+16), 32 rows, K=512 from LDS ----
  {
    f32x4 qacc[2] = {};
    f32x4 qaccm[2] = {};
#pragma unroll 2
    for (int ks = 0; ks < 16; ++ks) {
      half8v ah0 = *(const half8v*)&s1h[r][ks * 32 + g * 8];
      half8v al0 = *(const half8v*)&s1l[r][ks * 32 + g * 8];
      half8v ah1 = *(const half8v*)&s1h[16 + r][ks * 32 + g * 8];
      half8v al1 = *(const half8v*)&s1l[16 + r][ks * 32 + g * 8];
      half8v bhv = PB2h[(size_t)((ks * 8 + w) * 64) + lane];
      half8v blv = PB2l[(size_t)((ks * 8 + w) * 64) + lane];
      qaccm[0] = __builtin_amdgcn_mfma_f32_16x16x32_f16(al0, bhv, qaccm[0], 0, 0, 0);
      qaccm[0] = __builtin_amdgcn_mfma_f32_16x16x32_f16(ah0, blv, qaccm[0], 0, 0, 0);
      qacc[0]  = __builtin_amdgcn_mfma_f32_16x16x32_f16(ah0, bhv, qacc[0], 0, 0, 0);
      qaccm[1] = __builtin_amdgcn_mfma_f32_16x16x32_f16(al1, bhv, qaccm[1], 0, 0, 0);
      qaccm[1] = __builtin_amdgcn_mfma_f32_16x16x32_f16(ah1, blv, qaccm[1], 0, 0, 0);
      qacc[1]  = __builtin_amdgcn_mfma_f32_16x16x32_f16(ah1, bhv, qacc[1], 0, 0, 0);
    }
    int col = w * 16 + r;
    float as_ = att_s[col], ad_ = att_d[col];
    float ps[2][4], pd[2][4];
#pragma unroll
    for (int mt = 0; mt < 2; ++mt) {
#pragma unroll
      for (int i = 0; i < 4; ++i) {
        float v = qacc[mt][i] + qaccm[mt][i] * LO_INV;
        int row = rows0 + mt * 16 + g * 4 + i;
        if (row < nM) xw2[(size_t)(n0 + row) * 128 + col] = v;
        ps[mt][i] = v * as_;
        pd[mt][i] = v * ad_;
      }
    }
#pragma unroll
    for (int mt = 0; mt < 2; ++mt) {
#pragma unroll
      for (int i = 0; i < 4; ++i) {
        for (int off = 1; off < 16; off <<= 1) {
          ps[mt][i] += __shfl_xor(ps[mt][i], off);
          pd[mt][i] += __shfl_xor(pd[mt][i], off);
        }
      }
    }
    if (r == 0) {
#pragma unroll
      for (int mt = 0; mt < 2; ++mt) {
#pragma unroll
        for (int i = 0; i < 4; ++i) {
          int row = rows0 + mt * 16 + g * 4 + i;
          if (row < nM) {
            atomicAdd(&a_s[n0 + row], ps[mt][i]);
            atomicAdd(&a_d[n0 + row], pd[mt][i]);
          }
        }
      }
    }
  }
}

// ---------------------------------------------------------------------------
// Layer-2 aggregate + FUSED GRAPH MAX-POOL: instead of writing out2 (whose
// only consumer was the pool), atomicMax the elu output directly into
// pooled_u[g*128+c] using an order-preserving float->uint bijection (max is
// order-independent -> EXACT). Deletes out2 (20MB traffic), pool_part,
// pool_reduce, and gstart.
// ---------------------------------------------------------------------------
__global__ __launch_bounds__(256) void agg2_kernel(
    const float* __restrict__ xw, const float* __restrict__ a_src,
    const float* __restrict__ a_dst, const int* __restrict__ indptr,
    const int* __restrict__ srcs, const float* __restrict__ bias,
    const int* __restrict__ batch, unsigned* __restrict__ pooled_u) {
  int lane = threadIdx.x & 63;
  int n = blockIdx.x * 4 + (threadIdx.x >> 6);
  if (n >= N_NODES) return;
  int beg = indptr[n], end = indptr[n + 1];
  int deg = end - beg;
  float adn = a_dst[n];
  int half = lane >> 5, l32 = lane & 31;
  float4 acc = make_float4(0.f, 0.f, 0.f, 0.f);

  auto quads = [&](int s, float al, int jn) {
    int jj = 0;
    for (; jj + 4 <= jn; jj += 4) {
      int s0 = readlane_i(s, jj), s1 = readlane_i(s, jj + 1);
      int s2 = readlane_i(s, jj + 2), s3 = readlane_i(s, jj + 3);
      float a0 = readlane_f(al, jj), a1 = readlane_f(al, jj + 1);
      float a2 = readlane_f(al, jj + 2), a3 = readlane_f(al, jj + 3);
      int sh0 = half ? s1 : s0;   float ah0 = half ? a1 : a0;
      int sh1 = half ? s3 : s2;   float ah1 = half ? a3 : a2;
      float4 v0 = *(const float4*)&xw[(size_t)sh0 * HID + l32 * 4];
      float4 v1 = *(const float4*)&xw[(size_t)sh1 * HID + l32 * 4];
      acc.x += ah0 * v0.x; acc.y += ah0 * v0.y;
      acc.z += ah0 * v0.z; acc.w += ah0 * v0.w;
      acc.x += ah1 * v1.x; acc.y += ah1 * v1.y;
      acc.z += ah1 * v1.z; acc.w += ah1 * v1.w;
    }
    for (; jj + 2 <= jn; jj += 2) {
      int sa = readlane_i(s, jj), sb = readlane_i(s, jj + 1);
      float aa = readlane_f(al, jj), ab = readlane_f(al, jj + 1);
      int sh = half ? sb : sa;
      float ahx = half ? ab : aa;
      float4 v = *(const float4*)&xw[(size_t)sh * HID + l32 * 4];
      acc.x += ahx * v.x; acc.y += ahx * v.y; acc.z += ahx * v.z; acc.w += ahx * v.w;
    }
    if (jj < jn) {
      int sa = readlane_i(s, jj);
      float ahx = half ? 0.f : readlane_f(al, jj);
      float4 v = *(const float4*)&xw[(size_t)sa * HID + l32 * 4];
      acc.x += ahx * v.x; acc.y += ahx * v.y; acc.z += ahx * v.z; acc.w += ahx * v.w;
    }
  };

  if (deg <= 64) {
    int j = beg + lane;
    int s = 0;
    float e = -INFINITY;
    if (j < end) { s = srcs[j]; e = leaky(a_src[s] + adn); }
    float m = e;
    for (int off = 1; off < 64; off <<= 1) m = fmaxf(m, __shfl_xor(m, off));
    float x = (j < end) ? expf(e - m) : 0.f;
    float d = x;
    for (int off = 1; off < 64; off <<= 1) d += __shfl_xor(d, off);
    float al = x / (d + 1e-16f);
    quads(s, al, deg);
  } else {
    float m = -INFINITY;
    for (int j0 = beg; j0 < end; j0 += 64) {
      int j = j0 + lane;
      if (j < end) m = fmaxf(m, leaky(a_src[srcs[j]] + adn));
    }
    for (int off = 1; off < 64; off <<= 1) m = fmaxf(m, __shfl_xor(m, off));
    float d = 0.f;
    for (int j0 = beg; j0 < end; j0 += 64) {
      int j = j0 + lane;
      if (j < end) d += expf(leaky(a_src[srcs[j]] + adn) - m);
    }
    for (int off = 1; off < 64; off <<= 1) d += __shfl_xor(d, off);
    float rd = 1.f / (d + 1e-16f);
    for (int j0 = beg; j0 < end; j0 += 64) {
      int jn = min(64, end - j0);
      int j = j0 + lane;
      int s = 0;
      float al = 0.f;
      if (j < end) {
        s = srcs[j];
        al = expf(leaky(a_src[s] + adn) - m) * rd;
      }
      quads(s, al, jn);
    }
  }

  acc.x += __shfl_xor(acc.x, 32); acc.y += __shfl_xor(acc.y, 32);
  acc.z += __shfl_xor(acc.z, 32); acc.w += __shfl_xor(acc.w, 32);
  if (half == 0) {
    float4 b = *(const float4*)&bias[l32 * 4];
    int g = batch[n];
    unsigned* p = &pooled_u[(size_t)g * HID + l32 * 4];
    atomicMax(&p[0], encf(elu(acc.x + b.x)));
    atomicMax(&p[1], encf(elu(acc.y + b.y)));
    atomicMax(&p[2], encf(elu(acc.z + b.z)));
    atomicMax(&p[3], encf(elu(acc.w + b.w)));
  }
}

// ---------------------------------------------------------------------------
// Classifier head: decodes the uint-encoded pooled maxima.
// ---------------------------------------------------------------------------
__global__ __launch_bounds__(HID) void cls_kernel(const unsigned* __restrict__ pooled_u,
                                                  const float* __restrict__ w1,
                                                  const float* __restrict__ b1,
                                                  const float* __restrict__ w2,
                                                  const float* __restrict__ b2,
                                                  float* __restrict__ out) {
  int g = blockIdx.x, t = threadIdx.x;
  __shared__ float sp[HID], sh1[HID / 2];
  sp[t] = decf(pooled_u[(size_t)g * HID + t]);
  __syncthreads();
  if (t < HID / 2) {
    float s = b1[t];
    for (int k = 0; k < HID; ++k) s += sp[k] * w1[k * (HID / 2) + t];
    sh1[t] = fmaxf(s, 0.f);
  }
  __syncthreads();
  if (t < 2) {
    float o = b2[t];
    for (int k = 0; k < HID / 2; ++k) o += sh1[k] * w2[k * 2 + t];
    out[g * 2 + t] = o;
  }
}

// ---------------------------------------------------------------------------
extern "C" void kernel_launch(void* const* d_in, const int* in_sizes, int n_in,
                              void* d_out, int out_size, void* d_ws, size_t ws_size,
                              hipStream_t stream) {
  const float* x_scalar = (const float*)d_in[0];
  const int* x_opcode   = (const int*)d_in[1];
  const int* x_source   = (const int*)d_in[2];
  const int* x_sink     = (const int*)d_in[3];
  const int* x_string   = (const int*)d_in[4];
  const int* x_payload  = (const int*)d_in[5];
  const int* edge_index = (const int*)d_in[6];
  const int* batch      = (const int*)d_in[7];
  const float* emb_opcode = (const float*)d_in[8];
  const float* emb_source = (const float*)d_in[9];
  const float* emb_sink   = (const float*)d_in[10];
  const float* emb_string = (const float*)d_in[11];
  const float* emb_payload= (const float*)d_in[12];
  const float* ln_gamma = (const float*)d_in[13];
  const float* ln_beta  = (const float*)d_in[14];
  const float* W1       = (const float*)d_in[15];
  const float* att_src1 = (const float*)d_in[16];
  const float* att_dst1 = (const float*)d_in[17];
  const float* b1       = (const float*)d_in[18];
  const float* W2       = (const float*)d_in[19];
  const float* att_src2 = (const float*)d_in[20];
  const float* att_dst2 = (const float*)d_in[21];
  const float* b2       = (const float*)d_in[22];
  const float* cls_w1   = (const float*)d_in[23];
  const float* cls_b1   = (const float*)d_in[24];
  const float* cls_w2   = (const float*)d_in[25];
  const float* cls_b2   = (const float*)d_in[26];

  // aggh is f16 hi/lo; out2/pool_part/gstarts deleted (pool fused into agg2).
  auto total_bytes = [&](int chunk) -> size_t {
    size_t f = (size_t)N_NODES * IN_DIM + (size_t)N_NODES * HID +
               N_NODES * 4 * 2 + N_NODES * 2 + IN_DIM * 4 * 2;
    size_t ii = (N_NODES + 1) + N_NODES * 2 + TOT_EDGES + N_GRAPHS * HID;
    size_t f16b = ((size_t)2 * (PB2_ELEMS + PB1_ELEMS) +
                   (size_t)chunk * 4 * IN_DIM * 2) * sizeof(_Float16) + 64;
    return f * 4 + ii * 4 + f16b + 256;
  };
  int chunk = (ws_size >= total_bytes(N_NODES)) ? N_NODES : CHUNK_SMALL;

  float* h      = (float*)d_ws;                        // [N,176]
  _Float16* agghh = (_Float16*)(h + (size_t)N_NODES * IN_DIM);  // [chunk*704]
  _Float16* agghl = agghh + (size_t)chunk * 4 * IN_DIM;
  float* xw2    = (float*)(agghl + (size_t)chunk * 4 * IN_DIM); // [N,128]
  float* a1s    = xw2 + (size_t)N_NODES * HID;         // [N,4]
  float* a1d    = a1s + N_NODES * 4;
  float* was4   = a1d + N_NODES * 4;                   // [176*4]
  float* wad4   = was4 + IN_DIM * 4;                   // [176*4]
  int* indptr = (int*)(wad4 + IN_DIM * 4);             // [N+1]
  int* cnt    = indptr + (N_NODES + 1);                // [N]   -- zero from here
  int* cursor = cnt + N_NODES;                         // [N]
  float* a2s  = (float*)(cursor + N_NODES);            // [N]
  float* a2d  = a2s + N_NODES;                         // [N]
  unsigned* pooled_u = (unsigned*)(a2d + N_NODES);     // [G*128] -- zero to here
  int* srcs   = (int*)(pooled_u + N_GRAPHS * HID);     // [E+N]
  uintptr_t pal = ((uintptr_t)(srcs + TOT_EDGES) + 15) & ~(uintptr_t)15;
  _Float16* PB2h = (_Float16*)pal;                     // [65536]
  _Float16* PB2l = PB2h + PB2_ELEMS;                   // [65536]
  _Float16* PB1h = PB2l + PB2_ELEMS;                   // [98304]
  _Float16* PB1l = PB1h + PB1_ELEMS;                   // [98304]

  // zero cnt, cursor, a2s, a2d, pooled_u in one shot (contiguous).
  // pooled_u init 0 == enc(-inf-below-everything): every real value's
  // encoding is > 0, so atomicMax semantics match max-pool with -inf init.
  hipMemsetAsync(cnt, 0, (4 * (size_t)N_NODES + N_GRAPHS * HID) * sizeof(int),
                 stream);

  // L0: wasd alone (feats' only dependency; ~3us).
  wasd_kernel<<<(IN_DIM + 3) / 4, 256, 0, stream>>>(W1, att_src1, att_dst1,
                                                    was4, wad4);

  // L1: feats (long blocks FIRST) || pack_w1/w2 || count.
  feats_setup_kernel<<<L1_TOTAL, 256, 0, stream>>>(
      x_scalar, x_opcode, x_source, x_sink, x_string, x_payload,
      emb_opcode, emb_source, emb_sink, emb_string, emb_payload,
      ln_gamma, ln_beta, was4, wad4, W1, W2, edge_index,
      h, a1s, a1d, PB1h, PB1l, PB2h, PB2l, cnt);

  // L2: prefix scan (needs count).
  prefix_kernel<<<1, 1024, 0, stream>>>(cnt, indptr, N_NODES, TOT_EDGES);

  // L3: scatter alone (needs prefix; 1329 blocks, full machine).
  scatter_kernel<<<COUNT_BLOCKS, 256, 0, stream>>>(edge_index, indptr, cursor,
                                                   srcs);

  // Mid (serial): agg1h (f16 hi/lo out) then fused gemm1+gemm2 (32 rows/blk).
  for (int n0 = 0; n0 < N_NODES; n0 += chunk) {
    int nM = min(chunk, N_NODES - n0);
    agg1h_kernel<<<(nM + 3) / 4, 256, 0, stream>>>(h, a1s, a1d, indptr, srcs,
                                                   agghh, agghl, n0, nM);
    gemm_fused_kernel<<<(nM + 31) / 32, 512, 0, stream>>>(
        agghh, agghl, (const half8v*)PB1h, (const half8v*)PB1l, b1,
        (const half8v*)PB2h, (const half8v*)PB2l, att_src2, att_dst2,
        xw2, a2s, a2d, n0, nM);
  }

  // agg2 + fused graph max-pool (atomicMax on order-preserving uints).
  agg2_kernel<<<NB4, 256, 0, stream>>>(xw2, a2s, a2d, indptr, srcs, b2,
                                       batch, pooled_u);

  cls_kernel<<<N_GRAPHS, HID, 0, stream>>>(pooled_u, cls_w1, cls_b1, cls_w2,
                                           cls_b2, (float*)d_out);
}

// Round 16
// 349.051 us; speedup vs baseline: 1.1750x; 1.1750x over previous
//
#include <hip/hip_runtime.h>
#include <hip/hip_bf16.h>
#include <math.h>

// Problem constants (match reference setup_inputs()).
#define N_NODES 20000
#define N_EDGES 320000
#define N_GRAPHS 64
#define SEQ 20
#define SCALAR 16
#define EMB 32
#define HID 128
#define IN_DIM 176         // SCALAR + 5*EMB
#define TOT_EDGES (N_EDGES + N_NODES)  // with self loops
#define CHUNK_SMALL 10000  // fallback node chunk when workspace is tight
#define POOL_SLICES 32     // parallel slices per graph for max-pool

// f16 MFMA types
typedef _Float16 half8v __attribute__((ext_vector_type(8)));
typedef float f32x4 __attribute__((ext_vector_type(4)));
#define LO_SCALE 2048.0f
#define LO_INV (1.0f / 2048.0f)

// Pack-buffer element counts (f16 elems each, hi and lo separately)
#define PB2_ELEMS (16 * 8 * 64 * 8)      // [ks16][ntile8][lane64][j8] = 65536
#define PB1_ELEMS (4 * 6 * 8 * 64 * 8)   // [head4][ks6][ntile8][lane64][j8] = 98304

// Grid split constants.
#define COUNT_BLOCKS ((TOT_EDGES + 255) / 256)  // 1329
#define NB4 ((N_NODES + 3) / 4)               // 5000 feats blocks
// L1 layout: [0,NB4) feats; [NB4,NB4+48) pack_w1; [+32) pack_w2;
//            [+COUNT_BLOCKS) count; last gstart.
#define L1_PACK1 NB4
#define L1_PACK2 (NB4 + 48)
#define L1_COUNT (NB4 + 80)
#define L1_TOTAL (NB4 + 80 + COUNT_BLOCKS + 1)

__device__ inline float readlane_f(float v, int l) {
  return __uint_as_float(__builtin_amdgcn_readlane(__float_as_uint(v), l));
}
__device__ inline int readlane_i(int v, int l) {
  return __builtin_amdgcn_readlane(v, l);
}
__device__ inline float leaky(float e) { return e >= 0.f ? e : 0.2f * e; }
__device__ inline float elu(float v) { return v > 0.f ? v : expf(v) - 1.f; }

// ---------------------------------------------------------------------------
// L0: wasd precompute alone (feats' only dependency). 44 blocks.
// ---------------------------------------------------------------------------
__global__ __launch_bounds__(256) void wasd_kernel(
    const float* __restrict__ W1, const float* __restrict__ att_s1,
    const float* __restrict__ att_d1, float* __restrict__ was4,
    float* __restrict__ wad4) {
  int lane = threadIdx.x & 63;
  int k = blockIdx.x * 4 + (threadIdx.x >> 6);
  if (k >= IN_DIM) return;
  const float* wrow = W1 + (size_t)k * 512;
  float s[4], d[4];
#pragma unroll
  for (int hh = 0; hh < 4; ++hh) {
    float w0 = wrow[hh * 128 + lane], w1 = wrow[hh * 128 + 64 + lane];
    float a0 = att_s1[hh * 128 + lane], a1 = att_s1[hh * 128 + 64 + lane];
    float c0 = att_d1[hh * 128 + lane], c1 = att_d1[hh * 128 + 64 + lane];
    s[hh] = w0 * a0 + w1 * a1;
    d[hh] = w0 * c0 + w1 * c1;
  }
  for (int off = 1; off < 64; off <<= 1) {
#pragma unroll
    for (int hh = 0; hh < 4; ++hh) {
      s[hh] += __shfl_xor(s[hh], off);
      d[hh] += __shfl_xor(d[hh], off);
    }
  }
  if (lane == 0) {
    *(float4*)&was4[k * 4] = make_float4(s[0], s[1], s[2], s[3]);
    *(float4*)&wad4[k * 4] = make_float4(d[0], d[1], d[2], d[3]);
  }
}

// ---------------------------------------------------------------------------
// L1 (fused): feats+LN+att1 FIRST (5000 long blocks), then pack_w1/pack_w2,
// CSR degree count, gstart. All parts' inputs ready (wasd in L0; cnt
// pre-zeroed). Count's short blocks drain inside feats' runtime.
// ---------------------------------------------------------------------------
__global__ __launch_bounds__(256) void feats_setup_kernel(
    const float* __restrict__ xs,
    const int* __restrict__ i0, const int* __restrict__ i1,
    const int* __restrict__ i2, const int* __restrict__ i3,
    const int* __restrict__ i4,
    const float* __restrict__ t0, const float* __restrict__ t1,
    const float* __restrict__ t2, const float* __restrict__ t3,
    const float* __restrict__ t4,
    const float* __restrict__ gamma, const float* __restrict__ beta,
    const float* __restrict__ was4, const float* __restrict__ wad4,
    const float* __restrict__ W1, const float* __restrict__ W2,
    const int* __restrict__ edge_index, const int* __restrict__ batch,
    float* __restrict__ hout, float* __restrict__ a_s,
    float* __restrict__ a_d,
    _Float16* __restrict__ PB1h, _Float16* __restrict__ PB1l,
    _Float16* __restrict__ PB2h, _Float16* __restrict__ PB2l,
    int* __restrict__ cnt, int* __restrict__ gstarts) {
  int b = blockIdx.x;
  if (b >= NB4) {
    if (b < L1_PACK2) {
      // pack_w1: [hh4][ks6][ntile8][lane64][j8], K zero-padded to 192.
      int t = (b - L1_PACK1) * 256 + threadIdx.x;  // 12288 threads exactly
      int lane = t & 63, wi = t >> 6;
      int r = lane & 15, g = lane >> 4;
      int ntile = wi & 7, rem = wi >> 3;
      int ks = rem % 6, hh = rem / 6;
      int col = hh * 128 + ntile * 16 + r;
      size_t o = ((size_t)wi * 64 + lane) * 8;
#pragma unroll
      for (int j = 0; j < 8; ++j) {
        int k = ks * 32 + g * 8 + j;
        float v = (k < IN_DIM) ? W1[(size_t)k * 512 + col] : 0.f;
        _Float16 h = (_Float16)v;
        PB1h[o + j] = h;
        PB1l[o + j] = (_Float16)((v - (float)h) * LO_SCALE);
      }
    } else if (b < L1_COUNT) {
      // pack_w2: [ks16][ntile8][lane64][j8]
      int t = (b - L1_PACK2) * 256 + threadIdx.x;  // 8192 threads exactly
      int lane = t & 63, wi = t >> 6;
      int r = lane & 15, g = lane >> 4;
      int ks = wi >> 3, ntile = wi & 7;
      int col = ntile * 16 + r;
      size_t o = ((size_t)wi * 64 + lane) * 8;
#pragma unroll
      for (int j = 0; j < 8; ++j) {
        int k = ks * 32 + g * 8 + j;
        float v = W2[(size_t)k * 128 + col];
        _Float16 h = (_Float16)v;
        PB2h[o + j] = h;
        PB2l[o + j] = (_Float16)((v - (float)h) * LO_SCALE);
      }
    } else if (b < L1_COUNT + COUNT_BLOCKS) {
      // CSR degree count (cnt pre-zeroed by memset).
      int i = (b - L1_COUNT) * 256 + threadIdx.x;
      if (i < N_EDGES) {
        atomicAdd(&cnt[edge_index[N_EDGES + i]], 1);
      } else if (i < TOT_EDGES) {
        atomicAdd(&cnt[i - N_EDGES], 1);  // self loop dst = node
      }
    } else {
      // gstart: binary search graph boundaries in sorted batch.
      int t = threadIdx.x;
      if (t > N_GRAPHS) return;
      int lo = 0, hi = N_NODES;
      while (lo < hi) {
        int mid = (lo + hi) >> 1;
        if (batch[mid] < t) lo = mid + 1; else hi = mid;
      }
      gstarts[t] = lo;
    }
    return;
  }
  // feats+LN+att1, wave-per-node (4 nodes / block, zero barriers).
  int lane = threadIdx.x & 63;
  int w = threadIdx.x >> 6;
  int n = b * 4 + w;
  if (n >= N_NODES) return;
  __shared__ int sidx[4][100];
  {
    int j = lane;                       // 0..63 -> tabs 0..3
    int tab = j / 20, l = j - tab * 20;
    const int* ip = tab == 0 ? i0 : tab == 1 ? i1 : tab == 2 ? i2 : i3;
    sidx[w][j] = ip[n * SEQ + l];
    if (lane < 36) {
      int j2 = 64 + lane;               // 64..99 -> tabs 3,4
      int tab2 = j2 / 20, l2 = j2 - tab2 * 20;
      const int* ip2 = tab2 == 3 ? i3 : i4;
      sidx[w][j2] = ip2[n * SEQ + l2];
    }
  }
  bool l48 = lane < 48;
  float f0, f1, f2 = 0.f;
  if (lane < SCALAR) {
    f0 = xs[n * SCALAR + lane];
  } else {
    int tt = lane - SCALAR, tab = tt >> 5, d = tt & 31;  // tab 0 or 1
    const float* tp = tab == 0 ? t0 : t1;
    float sum = 0.f, cnt2 = 0.f;
#pragma unroll
    for (int l = 0; l < SEQ; ++l) {
      int id = sidx[w][tab * 20 + l];
      if (id != 0) { sum += tp[id * EMB + d]; cnt2 += 1.f; }
    }
    f0 = sum / (cnt2 + 1e-9f);
  }
  {
    int tt = 48 + lane, tab = tt >> 5, d = tt & 31;      // tab 1,2,3
    const float* tp = tab == 1 ? t1 : tab == 2 ? t2 : t3;
    float sum = 0.f, cnt2 = 0.f;
#pragma unroll
    for (int l = 0; l < SEQ; ++l) {
      int id = sidx[w][tab * 20 + l];
      if (id != 0) { sum += tp[id * EMB + d]; cnt2 += 1.f; }
    }
    f1 = sum / (cnt2 + 1e-9f);
  }
  if (l48) {
    int tt = 112 + lane, tab = tt >> 5, d = tt & 31;     // tab 3 or 4
    const float* tp = tab == 3 ? t3 : t4;
    float sum = 0.f, cnt2 = 0.f;
#pragma unroll
    for (int l = 0; l < SEQ; ++l) {
      int id = sidx[w][tab * 20 + l];
      if (id != 0) { sum += tp[id * EMB + d]; cnt2 += 1.f; }
    }
    f2 = sum / (cnt2 + 1e-9f);
  }
  float s = f0 + f1 + f2;  // f2==0 for lane>=48
  for (int off = 1; off < 64; off <<= 1) s += __shfl_xor(s, off);
  float mu = s / (float)IN_DIM;
  float v = (f0 - mu) * (f0 - mu) + (f1 - mu) * (f1 - mu) +
            (l48 ? (f2 - mu) * (f2 - mu) : 0.f);
  for (int off = 1; off < 64; off <<= 1) v += __shfl_xor(v, off);
  float rstd = 1.0f / sqrtf(v / (float)IN_DIM + 1e-5f);
  float hv0 = (f0 - mu) * rstd * gamma[lane] + beta[lane];
  float hv1 = (f1 - mu) * rstd * gamma[64 + lane] + beta[64 + lane];
  float hv2 = l48 ? (f2 - mu) * rstd * gamma[128 + lane] + beta[128 + lane] : 0.f;
  float* hr = hout + (size_t)n * IN_DIM;
  hr[lane] = hv0;
  hr[64 + lane] = hv1;
  if (l48) hr[128 + lane] = hv2;

  // Fused layer-1 attention logits: ps/pd[h] = h_row . was/wad[:,h]
  const float4* wsv = (const float4*)was4;
  const float4* wdv = (const float4*)wad4;
  float4 wsa = wsv[lane], wsb = wsv[64 + lane];
  float4 wsc = l48 ? wsv[128 + lane] : make_float4(0.f, 0.f, 0.f, 0.f);
  float4 wda = wdv[lane], wdb = wdv[64 + lane];
  float4 wdc = l48 ? wdv[128 + lane] : make_float4(0.f, 0.f, 0.f, 0.f);
  float ps0 = hv0 * wsa.x + hv1 * wsb.x + hv2 * wsc.x;
  float ps1 = hv0 * wsa.y + hv1 * wsb.y + hv2 * wsc.y;
  float ps2 = hv0 * wsa.z + hv1 * wsb.z + hv2 * wsc.z;
  float ps3 = hv0 * wsa.w + hv1 * wsb.w + hv2 * wsc.w;
  float pd0 = hv0 * wda.x + hv1 * wdb.x + hv2 * wdc.x;
  float pd1 = hv0 * wda.y + hv1 * wdb.y + hv2 * wdc.y;
  float pd2 = hv0 * wda.z + hv1 * wdb.z + hv2 * wdc.z;
  float pd3 = hv0 * wda.w + hv1 * wdb.w + hv2 * wdc.w;
  for (int off = 1; off < 64; off <<= 1) {
    ps0 += __shfl_xor(ps0, off); ps1 += __shfl_xor(ps1, off);
    ps2 += __shfl_xor(ps2, off); ps3 += __shfl_xor(ps3, off);
    pd0 += __shfl_xor(pd0, off); pd1 += __shfl_xor(pd1, off);
    pd2 += __shfl_xor(pd2, off); pd3 += __shfl_xor(pd3, off);
  }
  if (lane == 0) {
    *(float4*)&a_s[n * 4] = make_float4(ps0, ps1, ps2, ps3);
    *(float4*)&a_d[n * 4] = make_float4(pd0, pd1, pd2, pd3);
  }
}

// ---------------------------------------------------------------------------
// 1024-thread single block: per-thread partial sums + Hillis-Steele scan.
// ---------------------------------------------------------------------------
__global__ __launch_bounds__(1024) void prefix_kernel(const int* __restrict__ cnt,
                                                      int* __restrict__ indptr,
                                                      int n, int total) {
  __shared__ int ss[1024];
  int t = threadIdx.x;
  int per = (n + 1023) / 1024;
  int beg = t * per, end = min(beg + per, n);
  int s = 0;
  for (int i = beg; i < end; ++i) s += cnt[i];
  ss[t] = s;
  __syncthreads();
  for (int off = 1; off < 1024; off <<= 1) {
    int v = (t >= off) ? ss[t - off] : 0;
    __syncthreads();
    ss[t] += v;
    __syncthreads();
  }
  int run = ss[t] - s;  // exclusive prefix of this thread's range
  for (int i = beg; i < end; ++i) { indptr[i] = run; run += cnt[i]; }
  if (t == 0) indptr[n] = total;
}

// ---------------------------------------------------------------------------
// L3: CSR scatter alone (needs prefix). 1329 blocks, full machine.
// ---------------------------------------------------------------------------
__global__ void scatter_kernel(const int* __restrict__ edge_index,
                               const int* __restrict__ indptr,
                               int* __restrict__ cursor,
                               int* __restrict__ srcs) {
  int i = blockIdx.x * 256 + threadIdx.x;
  int s, d;
  if (i < N_EDGES) { s = edge_index[i]; d = edge_index[N_EDGES + i]; }
  else if (i < TOT_EDGES) { s = i - N_EDGES; d = s; }
  else return;
  int pos = indptr[d] + atomicAdd(&cursor[d], 1);
  srcs[pos] = s;
}

// ---------------------------------------------------------------------------
// Layer-1 softmax + aggregate h (176-dim) per head.
// Output PRE-SPLIT as f16 hi/lo planes (agghh/agghl, lo scaled x2048).
// ---------------------------------------------------------------------------
__global__ __launch_bounds__(256) void agg1h_kernel(
    const float* __restrict__ h, const float* __restrict__ a_src,
    const float* __restrict__ a_dst, const int* __restrict__ indptr,
    const int* __restrict__ srcs, _Float16* __restrict__ agghh,
    _Float16* __restrict__ agghl, int n0, int nM) {
  int lane = threadIdx.x & 63;
  int ln = blockIdx.x * 4 + (threadIdx.x >> 6);
  if (ln >= nM) return;
  int n = n0 + ln;
  int beg = indptr[n], end = indptr[n + 1];
  int deg = end - beg;
  float4 ad = *(const float4*)&a_dst[n * 4];
  bool l48 = lane < 48;
  float acc[4][3] = {};

  auto body = [&](int s, float al0, float al1, float al2, float al3) {
    const float* r = h + (size_t)s * IN_DIM;
    float v0 = r[lane];
    float v1 = r[64 + lane];
    float v2 = l48 ? r[128 + lane] : 0.f;
    acc[0][0] += al0 * v0; acc[0][1] += al0 * v1; acc[0][2] += al0 * v2;
    acc[1][0] += al1 * v0; acc[1][1] += al1 * v1; acc[1][2] += al1 * v2;
    acc[2][0] += al2 * v0; acc[2][1] += al2 * v1; acc[2][2] += al2 * v2;
    acc[3][0] += al3 * v0; acc[3][1] += al3 * v1; acc[3][2] += al3 * v2;
  };
  auto walk4 = [&](int s, float al0, float al1, float al2, float al3, int jn) {
    int jj = 0;
    for (; jj + 4 <= jn; jj += 4) {
      int sa = readlane_i(s, jj), sb = readlane_i(s, jj + 1);
      int sc = readlane_i(s, jj + 2), sd = readlane_i(s, jj + 3);
      float a0 = readlane_f(al0, jj), a1 = readlane_f(al1, jj);
      float a2 = readlane_f(al2, jj), a3 = readlane_f(al3, jj);
      float b0 = readlane_f(al0, jj + 1), b1 = readlane_f(al1, jj + 1);
      float b2 = readlane_f(al2, jj + 1), b3 = readlane_f(al3, jj + 1);
      float c0 = readlane_f(al0, jj + 2), c1 = readlane_f(al1, jj + 2);
      float c2 = readlane_f(al2, jj + 2), c3 = readlane_f(al3, jj + 2);
      float d0 = readlane_f(al0, jj + 3), d1 = readlane_f(al1, jj + 3);
      float d2 = readlane_f(al2, jj + 3), d3 = readlane_f(al3, jj + 3);
      body(sa, a0, a1, a2, a3);
      body(sb, b0, b1, b2, b3);
      body(sc, c0, c1, c2, c3);
      body(sd, d0, d1, d2, d3);
    }
    for (; jj < jn; ++jj) {
      int sa = readlane_i(s, jj);
      body(sa, readlane_f(al0, jj), readlane_f(al1, jj),
           readlane_f(al2, jj), readlane_f(al3, jj));
    }
  };

  if (deg <= 64) {
    int j = beg + lane;
    int s = 0;
    float e0 = -INFINITY, e1 = -INFINITY, e2 = -INFINITY, e3 = -INFINITY;
    if (j < end) {
      s = srcs[j];
      float4 as = *(const float4*)&a_src[s * 4];
      e0 = leaky(as.x + ad.x); e1 = leaky(as.y + ad.y);
      e2 = leaky(as.z + ad.z); e3 = leaky(as.w + ad.w);
    }
    float m0 = e0, m1 = e1, m2 = e2, m3 = e3;
    for (int off = 1; off < 64; off <<= 1) {
      m0 = fmaxf(m0, __shfl_xor(m0, off)); m1 = fmaxf(m1, __shfl_xor(m1, off));
      m2 = fmaxf(m2, __shfl_xor(m2, off)); m3 = fmaxf(m3, __shfl_xor(m3, off));
    }
    float x0 = (j < end) ? expf(e0 - m0) : 0.f;
    float x1 = (j < end) ? expf(e1 - m1) : 0.f;
    float x2 = (j < end) ? expf(e2 - m2) : 0.f;
    float x3 = (j < end) ? expf(e3 - m3) : 0.f;
    float d0 = x0, d1 = x1, d2 = x2, d3 = x3;
    for (int off = 1; off < 64; off <<= 1) {
      d0 += __shfl_xor(d0, off); d1 += __shfl_xor(d1, off);
      d2 += __shfl_xor(d2, off); d3 += __shfl_xor(d3, off);
    }
    float al0 = x0 / (d0 + 1e-16f), al1 = x1 / (d1 + 1e-16f);
    float al2 = x2 / (d2 + 1e-16f), al3 = x3 / (d3 + 1e-16f);
    walk4(s, al0, al1, al2, al3, deg);
  } else {
    float m0 = -INFINITY, m1 = -INFINITY, m2 = -INFINITY, m3 = -INFINITY;
    for (int j0 = beg; j0 < end; j0 += 64) {
      int j = j0 + lane;
      if (j < end) {
        int s = srcs[j];
        float4 as = *(const float4*)&a_src[s * 4];
        m0 = fmaxf(m0, leaky(as.x + ad.x)); m1 = fmaxf(m1, leaky(as.y + ad.y));
        m2 = fmaxf(m2, leaky(as.z + ad.z)); m3 = fmaxf(m3, leaky(as.w + ad.w));
      }
    }
    for (int off = 1; off < 64; off <<= 1) {
      m0 = fmaxf(m0, __shfl_xor(m0, off)); m1 = fmaxf(m1, __shfl_xor(m1, off));
      m2 = fmaxf(m2, __shfl_xor(m2, off)); m3 = fmaxf(m3, __shfl_xor(m3, off));
    }
    float d0 = 0.f, d1 = 0.f, d2 = 0.f, d3 = 0.f;
    for (int j0 = beg; j0 < end; j0 += 64) {
      int j = j0 + lane;
      if (j < end) {
        int s = srcs[j];
        float4 as = *(const float4*)&a_src[s * 4];
        d0 += expf(leaky(as.x + ad.x) - m0); d1 += expf(leaky(as.y + ad.y) - m1);
        d2 += expf(leaky(as.z + ad.z) - m2); d3 += expf(leaky(as.w + ad.w) - m3);
      }
    }
    for (int off = 1; off < 64; off <<= 1) {
      d0 += __shfl_xor(d0, off); d1 += __shfl_xor(d1, off);
      d2 += __shfl_xor(d2, off); d3 += __shfl_xor(d3, off);
    }
    float r0 = 1.f / (d0 + 1e-16f), r1 = 1.f / (d1 + 1e-16f);
    float r2 = 1.f / (d2 + 1e-16f), r3 = 1.f / (d3 + 1e-16f);
    for (int j0 = beg; j0 < end; j0 += 64) {
      int jn = min(64, end - j0);
      int j = j0 + lane;
      int s = 0;
      float al0 = 0.f, al1 = 0.f, al2 = 0.f, al3 = 0.f;
      if (j < end) {
        s = srcs[j];
        float4 as = *(const float4*)&a_src[s * 4];
        al0 = expf(leaky(as.x + ad.x) - m0) * r0;
        al1 = expf(leaky(as.y + ad.y) - m1) * r1;
        al2 = expf(leaky(as.z + ad.z) - m2) * r2;
        al3 = expf(leaky(as.w + ad.w) - m3) * r3;
      }
      walk4(s, al0, al1, al2, al3, jn);
    }
  }

  size_t base = (size_t)ln * (4 * IN_DIM);
#pragma unroll
  for (int hh = 0; hh < 4; ++hh) {
    size_t o0 = base + hh * IN_DIM + lane;
    float v0 = acc[hh][0], v1 = acc[hh][1];
    _Float16 h0 = (_Float16)v0, h1 = (_Float16)v1;
    agghh[o0] = h0;      agghl[o0] = (_Float16)((v0 - (float)h0) * LO_SCALE);
    agghh[o0 + 64] = h1; agghl[o0 + 64] = (_Float16)((v1 - (float)h1) * LO_SCALE);
    if (l48) {
      float v2 = acc[hh][2];
      _Float16 h2 = (_Float16)v2;
      agghh[o0 + 128] = h2;
      agghl[o0 + 128] = (_Float16)((v2 - (float)h2) * LO_SCALE);
    }
  }
}

// ---------------------------------------------------------------------------
// FUSED GEMM1+GEMM2, 32 ROWS/BLOCK. 512 threads = 8 waves; stage 1 wave
// w=(hh,colhalf) computes TWO 16-row groups; stage 2 wave w computes cols
// [w*16,+16) for 32 rows from LDS. Conversion-free both stages; out1 never
// touches HBM. Tail guard: rows >= nM never written.
// ---------------------------------------------------------------------------
__global__ __launch_bounds__(512) void gemm_fused_kernel(
    const _Float16* __restrict__ Ah, const _Float16* __restrict__ Al,
    const half8v* __restrict__ PB1h, const half8v* __restrict__ PB1l,
    const float* __restrict__ b1,
    const half8v* __restrict__ PB2h, const half8v* __restrict__ PB2l,
    const float* __restrict__ att_s, const float* __restrict__ att_d,
    float* __restrict__ xw2, float* __restrict__ a_s, float* __restrict__ a_d,
    int n0, int nM) {
  __shared__ _Float16 s1h[32][520];   // stride 520: 16B-aligned rows
  __shared__ _Float16 s1l[32][520];
  int lane = threadIdx.x & 63;
  int w = threadIdx.x >> 6;          // wave 0..7
  int rows0 = blockIdx.x * 32;
  if (rows0 >= nM) return;           // uniform per block
  int r = lane & 15, g = lane >> 4;
  // Clamp row-group-1 A pointers on the CHUNK_SMALL tail (discarded rows).
  int r1 = (rows0 + 16 + r < nM) ? (rows0 + 16 + r) : (rows0 + r);

  // ---- stage 1: out1[rows0..rows0+32) x (head hh, colhalf) ----
  {
    int hh = w >> 1, colhalf = w & 1;
    f32x4 acc[2][4] = {};
    f32x4 accm[2][4] = {};
    const _Float16* a0h = Ah + ((size_t)(rows0 + r) * 4 + hh) * IN_DIM;
    const _Float16* a0l = Al + ((size_t)(rows0 + r) * 4 + hh) * IN_DIM;
    const _Float16* a1h = Ah + ((size_t)r1 * 4 + hh) * IN_DIM;
    const _Float16* a1l = Al + ((size_t)r1 * 4 + hh) * IN_DIM;
#pragma unroll 2
    for (int ks = 0; ks < 6; ++ks) {
      int kg = ks * 32 + g * 8;
      int koff = (kg + 8 <= IN_DIM) ? kg : 0;  // clamp tail (B zeros kill it)
      half8v ah0 = *(const half8v*)(a0h + koff);
      half8v al0 = *(const half8v*)(a0l + koff);
      half8v ah1 = *(const half8v*)(a1h + koff);
      half8v al1 = *(const half8v*)(a1l + koff);
      const half8v* bh = PB1h + (size_t)(((hh * 6 + ks) * 8 + colhalf * 4) * 64) + lane;
      const half8v* bl = PB1l + (size_t)(((hh * 6 + ks) * 8 + colhalf * 4) * 64) + lane;
#pragma unroll
      for (int nt = 0; nt < 4; ++nt) {
        half8v bhv = bh[nt * 64], blv = bl[nt * 64];
        accm[0][nt] = __builtin_amdgcn_mfma_f32_16x16x32_f16(al0, bhv, accm[0][nt], 0, 0, 0);
        accm[0][nt] = __builtin_amdgcn_mfma_f32_16x16x32_f16(ah0, blv, accm[0][nt], 0, 0, 0);
        acc[0][nt]  = __builtin_amdgcn_mfma_f32_16x16x32_f16(ah0, bhv, acc[0][nt], 0, 0, 0);
        accm[1][nt] = __builtin_amdgcn_mfma_f32_16x16x32_f16(al1, bhv, accm[1][nt], 0, 0, 0);
        accm[1][nt] = __builtin_amdgcn_mfma_f32_16x16x32_f16(ah1, blv, accm[1][nt], 0, 0, 0);
        acc[1][nt]  = __builtin_amdgcn_mfma_f32_16x16x32_f16(ah1, bhv, acc[1][nt], 0, 0, 0);
      }
    }
#pragma unroll
    for (int nt = 0; nt < 4; ++nt) {
      int col = hh * 128 + colhalf * 64 + nt * 16 + r;
      float bb = b1[col];
#pragma unroll
      for (int mt = 0; mt < 2; ++mt) {
#pragma unroll
        for (int i = 0; i < 4; ++i) {
          int row = mt * 16 + g * 4 + i;  // 0..31 block-local
          if (rows0 + row < nM) {
            float o = elu(acc[mt][nt][i] + accm[mt][nt][i] * LO_INV + bb);
            _Float16 oh = (_Float16)o;
            s1h[row][col] = oh;
            s1l[row][col] = (_Float16)((o - (float)oh) * LO_SCALE);
          }
        }
      }
    }
  }
  __syncthreads();

  // ---- stage 2: xw2 cols [w*16, w*16+16), 32 rows, K=512 from LDS ----
  {
    f32x4 qacc[2] = {};
    f32x4 qaccm[2] = {};
#pragma unroll 2
    for (int ks = 0; ks < 16; ++ks) {
      half8v ah0 = *(const half8v*)&s1h[r][ks * 32 + g * 8];
      half8v al0 = *(const half8v*)&s1l[r][ks * 32 + g * 8];
      half8v ah1 = *(const half8v*)&s1h[16 + r][ks * 32 + g * 8];
      half8v al1 = *(const half8v*)&s1l[16 + r][ks * 32 + g * 8];
      half8v bhv = PB2h[(size_t)((ks * 8 + w) * 64) + lane];
      half8v blv = PB2l[(size_t)((ks * 8 + w) * 64) + lane];
      qaccm[0] = __builtin_amdgcn_mfma_f32_16x16x32_f16(al0, bhv, qaccm[0], 0, 0, 0);
      qaccm[0] = __builtin_amdgcn_mfma_f32_16x16x32_f16(ah0, blv, qaccm[0], 0, 0, 0);
      qacc[0]  = __builtin_amdgcn_mfma_f32_16x16x32_f16(ah0, bhv, qacc[0], 0, 0, 0);
      qaccm[1] = __builtin_amdgcn_mfma_f32_16x16x32_f16(al1, bhv, qaccm[1], 0, 0, 0);
      qaccm[1] = __builtin_amdgcn_mfma_f32_16x16x32_f16(ah1, blv, qaccm[1], 0, 0, 0);
      qacc[1]  = __builtin_amdgcn_mfma_f32_16x16x32_f16(ah1, bhv, qacc[1], 0, 0, 0);
    }
    int col = w * 16 + r;
    float as_ = att_s[col], ad_ = att_d[col];
    float ps[2][4], pd[2][4];
#pragma unroll
    for (int mt = 0; mt < 2; ++mt) {
#pragma unroll
      for (int i = 0; i < 4; ++i) {
        float v = qacc[mt][i] + qaccm[mt][i] * LO_INV;
        int row = rows0 + mt * 16 + g * 4 + i;
        if (row < nM) xw2[(size_t)(n0 + row) * 128 + col] = v;
        ps[mt][i] = v * as_;
        pd[mt][i] = v * ad_;
      }
    }
#pragma unroll
    for (int mt = 0; mt < 2; ++mt) {
#pragma unroll
      for (int i = 0; i < 4; ++i) {
        for (int off = 1; off < 16; off <<= 1) {
          ps[mt][i] += __shfl_xor(ps[mt][i], off);
          pd[mt][i] += __shfl_xor(pd[mt][i], off);
        }
      }
    }
    if (r == 0) {
#pragma unroll
      for (int mt = 0; mt < 2; ++mt) {
#pragma unroll
        for (int i = 0; i < 4; ++i) {
          int row = rows0 + mt * 16 + g * 4 + i;
          if (row < nM) {
            atomicAdd(&a_s[n0 + row], ps[mt][i]);
            atomicAdd(&a_d[n0 + row], pd[mt][i]);
          }
        }
      }
    }
  }
}

// ---------------------------------------------------------------------------
// Layer-2 aggregate: H=1, C=128. Half-wave per edge; 4 edges/iter.
// ---------------------------------------------------------------------------
__global__ __launch_bounds__(256) void agg2_kernel(
    const float* __restrict__ xw, const float* __restrict__ a_src,
    const float* __restrict__ a_dst, const int* __restrict__ indptr,
    const int* __restrict__ srcs, const float* __restrict__ bias,
    float* __restrict__ out) {
  int lane = threadIdx.x & 63;
  int n = blockIdx.x * 4 + (threadIdx.x >> 6);
  if (n >= N_NODES) return;
  int beg = indptr[n], end = indptr[n + 1];
  int deg = end - beg;
  float adn = a_dst[n];
  int half = lane >> 5, l32 = lane & 31;
  float4 acc = make_float4(0.f, 0.f, 0.f, 0.f);

  auto quads = [&](int s, float al, int jn) {
    int jj = 0;
    for (; jj + 4 <= jn; jj += 4) {
      int s0 = readlane_i(s, jj), s1 = readlane_i(s, jj + 1);
      int s2 = readlane_i(s, jj + 2), s3 = readlane_i(s, jj + 3);
      float a0 = readlane_f(al, jj), a1 = readlane_f(al, jj + 1);
      float a2 = readlane_f(al, jj + 2), a3 = readlane_f(al, jj + 3);
      int sh0 = half ? s1 : s0;   float ah0 = half ? a1 : a0;
      int sh1 = half ? s3 : s2;   float ah1 = half ? a3 : a2;
      float4 v0 = *(const float4*)&xw[(size_t)sh0 * HID + l32 * 4];
      float4 v1 = *(const float4*)&xw[(size_t)sh1 * HID + l32 * 4];
      acc.x += ah0 * v0.x; acc.y += ah0 * v0.y;
      acc.z += ah0 * v0.z; acc.w += ah0 * v0.w;
      acc.x += ah1 * v1.x; acc.y += ah1 * v1.y;
      acc.z += ah1 * v1.z; acc.w += ah1 * v1.w;
    }
    for (; jj + 2 <= jn; jj += 2) {
      int sa = readlane_i(s, jj), sb = readlane_i(s, jj + 1);
      float aa = readlane_f(al, jj), ab = readlane_f(al, jj + 1);
      int sh = half ? sb : sa;
      float ahx = half ? ab : aa;
      float4 v = *(const float4*)&xw[(size_t)sh * HID + l32 * 4];
      acc.x += ahx * v.x; acc.y += ahx * v.y; acc.z += ahx * v.z; acc.w += ahx * v.w;
    }
    if (jj < jn) {
      int sa = readlane_i(s, jj);
      float ahx = half ? 0.f : readlane_f(al, jj);
      float4 v = *(const float4*)&xw[(size_t)sa * HID + l32 * 4];
      acc.x += ahx * v.x; acc.y += ahx * v.y; acc.z += ahx * v.z; acc.w += ahx * v.w;
    }
  };

  if (deg <= 64) {
    int j = beg + lane;
    int s = 0;
    float e = -INFINITY;
    if (j < end) { s = srcs[j]; e = leaky(a_src[s] + adn); }
    float m = e;
    for (int off = 1; off < 64; off <<= 1) m = fmaxf(m, __shfl_xor(m, off));
    float x = (j < end) ? expf(e - m) : 0.f;
    float d = x;
    for (int off = 1; off < 64; off <<= 1) d += __shfl_xor(d, off);
    float al = x / (d + 1e-16f);
    quads(s, al, deg);
  } else {
    float m = -INFINITY;
    for (int j0 = beg; j0 < end; j0 += 64) {
      int j = j0 + lane;
      if (j < end) m = fmaxf(m, leaky(a_src[srcs[j]] + adn));
    }
    for (int off = 1; off < 64; off <<= 1) m = fmaxf(m, __shfl_xor(m, off));
    float d = 0.f;
    for (int j0 = beg; j0 < end; j0 += 64) {
      int j = j0 + lane;
      if (j < end) d += expf(leaky(a_src[srcs[j]] + adn) - m);
    }
    for (int off = 1; off < 64; off <<= 1) d += __shfl_xor(d, off);
    float rd = 1.f / (d + 1e-16f);
    for (int j0 = beg; j0 < end; j0 += 64) {
      int jn = min(64, end - j0);
      int j = j0 + lane;
      int s = 0;
      float al = 0.f;
      if (j < end) {
        s = srcs[j];
        al = expf(leaky(a_src[s] + adn) - m) * rd;
      }
      quads(s, al, jn);
    }
  }

  acc.x += __shfl_xor(acc.x, 32); acc.y += __shfl_xor(acc.y, 32);
  acc.z += __shfl_xor(acc.z, 32); acc.w += __shfl_xor(acc.w, 32);
  if (half == 0) {
    float4 b = *(const float4*)&bias[l32 * 4];
    float4 o;
    o.x = elu(acc.x + b.x); o.y = elu(acc.y + b.y);
    o.z = elu(acc.z + b.z); o.w = elu(acc.w + b.w);
    *(float4*)&out[(size_t)n * HID + l32 * 4] = o;
  }
}

// ---------------------------------------------------------------------------
// Two-stage max-pool per graph, classifier head.
// (Round-15 lesson: direct atomicMax pooling — 2.56M atomics into 8K
//  addresses — regressed 351.8->410 via L2 RMW serialization. Keep the
//  hierarchical two-stage reduction.)
// ---------------------------------------------------------------------------
__global__ __launch_bounds__(HID) void pool_part_kernel(
    const float* __restrict__ out2, const int* __restrict__ gstarts,
    float* __restrict__ part) {
  int g = blockIdx.x, s = blockIdx.y, t = threadIdx.x;
  int beg = gstarts[g], end = gstarts[g + 1];
  int len = end - beg;
  int b0 = beg + (int)(((long long)len * s) / POOL_SLICES);
  int b1 = beg + (int)(((long long)len * (s + 1)) / POOL_SLICES);
  float m = -INFINITY;
  for (int n = b0; n < b1; ++n) m = fmaxf(m, out2[(size_t)n * HID + t]);
  part[((size_t)g * POOL_SLICES + s) * HID + t] = m;
}

__global__ __launch_bounds__(HID) void pool_reduce_kernel(
    const float* __restrict__ part, float* __restrict__ pooled) {
  int g = blockIdx.x, t = threadIdx.x;
  float m = -INFINITY;
#pragma unroll
  for (int s = 0; s < POOL_SLICES; ++s)
    m = fmaxf(m, part[((size_t)g * POOL_SLICES + s) * HID + t]);
  pooled[g * HID + t] = m;
}

__global__ __launch_bounds__(HID) void cls_kernel(const float* __restrict__ pooled,
                                                  const float* __restrict__ w1,
                                                  const float* __restrict__ b1,
                                                  const float* __restrict__ w2,
                                                  const float* __restrict__ b2,
                                                  float* __restrict__ out) {
  int g = blockIdx.x, t = threadIdx.x;
  __shared__ float sp[HID], sh1[HID / 2];
  sp[t] = pooled[g * HID + t];
  __syncthreads();
  if (t < HID / 2) {
    float s = b1[t];
    for (int k = 0; k < HID; ++k) s += sp[k] * w1[k * (HID / 2) + t];
    sh1[t] = fmaxf(s, 0.f);
  }
  __syncthreads();
  if (t < 2) {
    float o = b2[t];
    for (int k = 0; k < HID / 2; ++k) o += sh1[k] * w2[k * 2 + t];
    out[g * 2 + t] = o;
  }
}

// ---------------------------------------------------------------------------
extern "C" void kernel_launch(void* const* d_in, const int* in_sizes, int n_in,
                              void* d_out, int out_size, void* d_ws, size_t ws_size,
                              hipStream_t stream) {
  const float* x_scalar = (const float*)d_in[0];
  const int* x_opcode   = (const int*)d_in[1];
  const int* x_source   = (const int*)d_in[2];
  const int* x_sink     = (const int*)d_in[3];
  const int* x_string   = (const int*)d_in[4];
  const int* x_payload  = (const int*)d_in[5];
  const int* edge_index = (const int*)d_in[6];
  const int* batch      = (const int*)d_in[7];
  const float* emb_opcode = (const float*)d_in[8];
  const float* emb_source = (const float*)d_in[9];
  const float* emb_sink   = (const float*)d_in[10];
  const float* emb_string = (const float*)d_in[11];
  const float* emb_payload= (const float*)d_in[12];
  const float* ln_gamma = (const float*)d_in[13];
  const float* ln_beta  = (const float*)d_in[14];
  const float* W1       = (const float*)d_in[15];
  const float* att_src1 = (const float*)d_in[16];
  const float* att_dst1 = (const float*)d_in[17];
  const float* b1       = (const float*)d_in[18];
  const float* W2       = (const float*)d_in[19];
  const float* att_src2 = (const float*)d_in[20];
  const float* att_dst2 = (const float*)d_in[21];
  const float* b2       = (const float*)d_in[22];
  const float* cls_w1   = (const float*)d_in[23];
  const float* cls_b1   = (const float*)d_in[24];
  const float* cls_w2   = (const float*)d_in[25];
  const float* cls_b2   = (const float*)d_in[26];

  // aggh is f16 hi/lo (same total bytes as the old f32 buffer).
  auto total_bytes = [&](int chunk) -> size_t {
    size_t f = (size_t)N_NODES * IN_DIM + (size_t)N_NODES * HID * 2 +
               N_NODES * 4 * 2 + N_NODES * 2 + IN_DIM * 4 * 2 + N_GRAPHS * HID;
    size_t ii = (N_NODES + 1) + N_NODES * 2 + TOT_EDGES + (N_GRAPHS + 1);
    size_t f16b = ((size_t)2 * (PB2_ELEMS + PB1_ELEMS) +
                   (size_t)chunk * 4 * IN_DIM * 2) * sizeof(_Float16) + 64;
    size_t poolb = (size_t)N_GRAPHS * POOL_SLICES * HID * 4 + 32;
    return f * 4 + ii * 4 + f16b + poolb + 256;
  };
  int chunk = (ws_size >= total_bytes(N_NODES)) ? N_NODES : CHUNK_SMALL;

  float* h      = (float*)d_ws;                        // [N,176]
  _Float16* agghh = (_Float16*)(h + (size_t)N_NODES * IN_DIM);  // [chunk*704]
  _Float16* agghl = agghh + (size_t)chunk * 4 * IN_DIM;
  float* xw2    = (float*)(agghl + (size_t)chunk * 4 * IN_DIM); // [N,128]
  float* out2   = xw2 + (size_t)N_NODES * HID;         // [N,128]
  float* a1s    = out2 + (size_t)N_NODES * HID;        // [N,4]
  float* a1d    = a1s + N_NODES * 4;
  float* was4   = a1d + N_NODES * 4;                   // [176*4]
  float* wad4   = was4 + IN_DIM * 4;                   // [176*4]
  float* pooled = wad4 + IN_DIM * 4;                   // [G,128]
  int* indptr = (int*)(pooled + N_GRAPHS * HID);       // [N+1]
  int* cnt    = indptr + (N_NODES + 1);                // [N]   (zeroed)
  int* cursor = cnt + N_NODES;                         // [N]   (zeroed)
  float* a2s  = (float*)(cursor + N_NODES);            // [N]   (zeroed)
  float* a2d  = a2s + N_NODES;                         // [N]   (zeroed)
  int* srcs   = (int*)(a2d + N_NODES);                 // [E+N]
  int* gstarts= srcs + TOT_EDGES;                      // [G+1]
  uintptr_t pal = ((uintptr_t)(gstarts + N_GRAPHS + 1) + 15) & ~(uintptr_t)15;
  _Float16* PB2h = (_Float16*)pal;                     // [65536]
  _Float16* PB2l = PB2h + PB2_ELEMS;                   // [65536]
  _Float16* PB1h = PB2l + PB2_ELEMS;                   // [98304]
  _Float16* PB1l = PB1h + PB1_ELEMS;                   // [98304]
  uintptr_t ppal = ((uintptr_t)(PB1l + PB1_ELEMS) + 15) & ~(uintptr_t)15;
  float* pool_part = (float*)ppal;                     // [G*32*128]

  // zero cnt, cursor, a2s, a2d in one shot (contiguous)
  hipMemsetAsync(cnt, 0, 4 * N_NODES * sizeof(int), stream);

  // L0: wasd alone (feats' only dependency; ~3us).
  wasd_kernel<<<(IN_DIM + 3) / 4, 256, 0, stream>>>(W1, att_src1, att_dst1,
                                                    was4, wad4);

  // L1: feats (long blocks FIRST) || pack_w1/w2 || count || gstart.
  feats_setup_kernel<<<L1_TOTAL, 256, 0, stream>>>(
      x_scalar, x_opcode, x_source, x_sink, x_string, x_payload,
      emb_opcode, emb_source, emb_sink, emb_string, emb_payload,
      ln_gamma, ln_beta, was4, wad4, W1, W2, edge_index, batch,
      h, a1s, a1d, PB1h, PB1l, PB2h, PB2l, cnt, gstarts);

  // L2: prefix scan (needs count).
  prefix_kernel<<<1, 1024, 0, stream>>>(cnt, indptr, N_NODES, TOT_EDGES);

  // L3: scatter alone (needs prefix; 1329 blocks, full machine).
  scatter_kernel<<<COUNT_BLOCKS, 256, 0, stream>>>(edge_index, indptr, cursor,
                                                   srcs);

  // Mid (serial): agg1h (f16 hi/lo out) then fused gemm1+gemm2 (32 rows/blk).
  for (int n0 = 0; n0 < N_NODES; n0 += chunk) {
    int nM = min(chunk, N_NODES - n0);
    agg1h_kernel<<<(nM + 3) / 4, 256, 0, stream>>>(h, a1s, a1d, indptr, srcs,
                                                   agghh, agghl, n0, nM);
    gemm_fused_kernel<<<(nM + 31) / 32, 512, 0, stream>>>(
        agghh, agghl, (const half8v*)PB1h, (const half8v*)PB1l, b1,
        (const half8v*)PB2h, (const half8v*)PB2l, att_src2, att_dst2,
        xw2, a2s, a2d, n0, nM);
  }

  agg2_kernel<<<NB4, 256, 0, stream>>>(xw2, a2s, a2d, indptr, srcs, b2, out2);

  pool_part_kernel<<<dim3(N_GRAPHS, POOL_SLICES), HID, 0, stream>>>(out2, gstarts, pool_part);
  pool_reduce_kernel<<<N_GRAPHS, HID, 0, stream>>>(pool_part, pooled);
  cls_kernel<<<N_GRAPHS, HID, 0, stream>>>(pooled, cls_w1, cls_b1, cls_w2, cls_b2, (float*)d_out);
}